// Round 3
// baseline (136.288 us; speedup 1.0000x reference)
//
#include <hip/hip_runtime.h>
#include <hip/hip_bf16.h>

typedef __bf16 bf16x8 __attribute__((ext_vector_type(8)));
typedef float  f32x4  __attribute__((ext_vector_type(4)));

#define DE_   64
#define DV_   64
#define DC_   32
#define DOUT_ 64
#define DIN_  224
#define NFRAG 28   // 7 k-steps * 4 n-tiles

// Pre-swizzle W ([224][64] f32 row-major) into bf16 MFMA B-fragment order:
// frag f = ks*4+nt ; lane holds B[k][col] with col = nt*16+(lane&15),
// k = ks*32 + (lane>>4)*8 + j, j=0..7 contiguous -> 16B per lane.
__global__ void prep_w_kernel(const float* __restrict__ W, __bf16* __restrict__ wf) {
    int f    = blockIdx.x;          // 0..27
    int lane = threadIdx.x;         // 0..63
    int ks = f >> 2, nt = f & 3;
    int col = nt * 16 + (lane & 15);
    int k0  = ks * 32 + (lane >> 4) * 8;
    bf16x8 v;
#pragma unroll
    for (int j = 0; j < 8; ++j)
        v[j] = (__bf16)W[(k0 + j) * DOUT_ + col];
    reinterpret_cast<bf16x8*>(wf)[f * 64 + lane] = v;
}

// One wave per 16-edge tile. 12500 blocks x 256 threads = 50000 waves.
__global__ __launch_bounds__(256, 4)
void edge_mlp_kernel(const float* __restrict__ edata,
                     const float* __restrict__ vdata,
                     const float* __restrict__ cdata,
                     const int*   __restrict__ snd,
                     const int*   __restrict__ rcv,
                     const __bf16* __restrict__ wf,
                     const float* __restrict__ bias,
                     float* __restrict__ out,
                     int NV, int n_tiles, int tiles_per_batch) {
    __shared__ bf16x8 wlds[NFRAG * 64];   // 28 KB

    const int tid  = threadIdx.x;
    const int lane = tid & 63;
    const int tile = blockIdx.x * (blockDim.x >> 6) + (tid >> 6);
    const bool active = tile < n_tiles;

    const int lr = lane & 15;   // A-row within tile / D-col within n-tile
    const int lg = lane >> 4;   // k-group
    const int kl = lg * 8;

    const int  b   = (tile >= tiles_per_batch) ? 1 : 0;
    const long row = active ? ((long)tile * 16 + lr) : 0;

    // Kick off the dependent chain immediately.
    const int s = snd[row];
    const int r = rcv[row];

    // Independent loads: edata (ks=0,1) and context (ks=6).
    float4 f0[7], f1[7];
#pragma unroll
    for (int ks = 0; ks < 2; ++ks) {
        const float* p = edata + row * DE_ + ks * 32 + kl;
        f0[ks] = *reinterpret_cast<const float4*>(p);
        f1[ks] = *reinterpret_cast<const float4*>(p + 4);
    }
    {
        const float* p = cdata + b * DC_ + kl;
        f0[6] = *reinterpret_cast<const float4*>(p);
        f1[6] = *reinterpret_cast<const float4*>(p + 4);
    }
    float bias_v[4];
#pragma unroll
    for (int nt = 0; nt < 4; ++nt) bias_v[nt] = bias[nt * 16 + lr];

    // Stage W into LDS (hides id-load latency under this + the barrier).
    {
        const bf16x8* wsrc = reinterpret_cast<const bf16x8*>(wf);
#pragma unroll
        for (int i = 0; i < 7; ++i)
            wlds[i * 256 + tid] = wsrc[i * 256 + tid];
    }
    __syncthreads();

    // Gathered loads (ids ready by now).
    const float* vb = vdata + (long)b * NV * DV_;
#pragma unroll
    for (int ks = 2; ks < 6; ++ks) {
        const float* p = (ks < 4) ? (vb + (long)s * DV_ + (ks - 2) * 32 + kl)
                                  : (vb + (long)r * DV_ + (ks - 4) * 32 + kl);
        f0[ks] = *reinterpret_cast<const float4*>(p);
        f1[ks] = *reinterpret_cast<const float4*>(p + 4);
    }

    f32x4 acc[4];
#pragma unroll
    for (int nt = 0; nt < 4; ++nt) acc[nt] = f32x4{0.f, 0.f, 0.f, 0.f};

#pragma unroll
    for (int ks = 0; ks < 7; ++ks) {
        bf16x8 a;
        a[0] = (__bf16)f0[ks].x; a[1] = (__bf16)f0[ks].y;
        a[2] = (__bf16)f0[ks].z; a[3] = (__bf16)f0[ks].w;
        a[4] = (__bf16)f1[ks].x; a[5] = (__bf16)f1[ks].y;
        a[6] = (__bf16)f1[ks].z; a[7] = (__bf16)f1[ks].w;
#pragma unroll
        for (int nt = 0; nt < 4; ++nt) {
            bf16x8 w = wlds[(ks * 4 + nt) * 64 + lane];
            acc[nt] = __builtin_amdgcn_mfma_f32_16x16x32_bf16(a, w, acc[nt], 0, 0, 0);
        }
    }

    if (!active) return;

    // D layout (m89): col = lane&15 (+16*nt), row = (lane>>4)*4 + j
    const long rb = (long)tile * 16;
#pragma unroll
    for (int nt = 0; nt < 4; ++nt) {
#pragma unroll
        for (int j = 0; j < 4; ++j) {
            float v = acc[nt][j] + bias_v[nt];
            out[(rb + lg * 4 + j) * DOUT_ + nt * 16 + lr] = v > 0.f ? v : 0.f;
        }
    }
}

extern "C" void kernel_launch(void* const* d_in, const int* in_sizes, int n_in,
                              void* d_out, int out_size, void* d_ws, size_t ws_size,
                              hipStream_t stream) {
    const float* edata = (const float*)d_in[0];
    const float* vdata = (const float*)d_in[1];
    const float* cdata = (const float*)d_in[2];
    const int*   snd   = (const int*)d_in[3];
    const int*   rcv   = (const int*)d_in[4];
    const float* W     = (const float*)d_in[5];
    const float* bias  = (const float*)d_in[6];
    float* out = (float*)d_out;

    const int Etot = in_sizes[3];              // B*E = 800000
    const int Bb   = in_sizes[2] / DC_;        // 2
    const int E    = Etot / Bb;                // 400000
    const int NV   = in_sizes[1] / (Bb * DV_); // 50000
    const int n_tiles = (Etot + 15) / 16;      // 50000
    const int tiles_per_batch = E / 16;        // 25000

    __bf16* wf = (__bf16*)d_ws;                // 28 KB fragment buffer

    hipLaunchKernelGGL(prep_w_kernel, dim3(NFRAG), dim3(64), 0, stream, W, wf);

    const int waves_per_block = 4;             // 256 threads
    const int blocks = (n_tiles + waves_per_block - 1) / waves_per_block;
    hipLaunchKernelGGL(edge_mlp_kernel, dim3(blocks), dim3(256), 0, stream,
                       edata, vdata, cdata, snd, rcv, wf, bias, out,
                       NV, n_tiles, tiles_per_batch);
}

// Round 4
// 133.987 us; speedup vs baseline: 1.0172x; 1.0172x over previous
//
#include <hip/hip_runtime.h>
#include <hip/hip_bf16.h>

typedef __bf16 bf16x8 __attribute__((ext_vector_type(8)));
typedef float  f32x4  __attribute__((ext_vector_type(4)));

#define DE_   64
#define DV_   64
#define DC_   32
#define DOUT_ 64
#define DIN_  224
#define NFRAG 28   // 7 k-steps * 4 n-tiles

// Pre-swizzle W ([224][64] f32 row-major) into bf16 MFMA B-fragment order:
// frag f = ks*4+nt ; lane holds B[k][col] with col = nt*16+(lane&15),
// k = ks*32 + (lane>>4)*8 + j, j=0..7 contiguous -> 16B per lane.
__global__ void prep_w_kernel(const float* __restrict__ W, __bf16* __restrict__ wf) {
    int f    = blockIdx.x;          // 0..27
    int lane = threadIdx.x;         // 0..63
    int ks = f >> 2, nt = f & 3;
    int col = nt * 16 + (lane & 15);
    int k0  = ks * 32 + (lane >> 4) * 8;
    bf16x8 v;
#pragma unroll
    for (int j = 0; j < 8; ++j)
        v[j] = (__bf16)W[(k0 + j) * DOUT_ + col];
    reinterpret_cast<bf16x8*>(wf)[f * 64 + lane] = v;
}

// One wave per 16-edge tile. 1024-thread blocks (16 waves) so the 28 KB LDS
// W-copy is amortized over 16 waves: 2 blocks/CU = 32 waves/CU = 100% occ.
__global__ __launch_bounds__(1024, 2)
void edge_mlp_kernel(const float* __restrict__ edata,
                     const float* __restrict__ vdata,
                     const float* __restrict__ cdata,
                     const int*   __restrict__ snd,
                     const int*   __restrict__ rcv,
                     const __bf16* __restrict__ wf,
                     const float* __restrict__ bias,
                     float* __restrict__ out,
                     int NV, int n_tiles, int tiles_per_batch) {
    __shared__ bf16x8 wlds[NFRAG * 64];   // 28 KB

    const int tid  = threadIdx.x;
    const int lane = tid & 63;
    const int tile = blockIdx.x * (blockDim.x >> 6) + (tid >> 6);
    const bool active = tile < n_tiles;

    const int lr = lane & 15;   // A-row within tile / D-col within n-tile
    const int lg = lane >> 4;   // k-group
    const int kl = lg * 8;

    const int  b   = (tile >= tiles_per_batch) ? 1 : 0;
    const long row = active ? ((long)tile * 16 + lr) : 0;

    // Kick off the dependent chain immediately.
    const int s = snd[row];
    const int r = rcv[row];

    // Independent loads: edata (ks=0,1) and context (ks=6).
    float4 f0[7], f1[7];
#pragma unroll
    for (int ks = 0; ks < 2; ++ks) {
        const float* p = edata + row * DE_ + ks * 32 + kl;
        f0[ks] = *reinterpret_cast<const float4*>(p);
        f1[ks] = *reinterpret_cast<const float4*>(p + 4);
    }
    {
        const float* p = cdata + b * DC_ + kl;
        f0[6] = *reinterpret_cast<const float4*>(p);
        f1[6] = *reinterpret_cast<const float4*>(p + 4);
    }
    float bias_v[4];
#pragma unroll
    for (int nt = 0; nt < 4; ++nt) bias_v[nt] = bias[nt * 16 + lr];

    // Stage W into LDS (hides id-load latency under this + the barrier).
    {
        const bf16x8* wsrc = reinterpret_cast<const bf16x8*>(wf);
#pragma unroll
        for (int i = tid; i < NFRAG * 64; i += 1024)
            wlds[i] = wsrc[i];
    }
    __syncthreads();

    // Gathered loads (ids ready by now).
    const float* vb = vdata + (long)b * NV * DV_;
#pragma unroll
    for (int ks = 2; ks < 6; ++ks) {
        const float* p = (ks < 4) ? (vb + (long)s * DV_ + (ks - 2) * 32 + kl)
                                  : (vb + (long)r * DV_ + (ks - 4) * 32 + kl);
        f0[ks] = *reinterpret_cast<const float4*>(p);
        f1[ks] = *reinterpret_cast<const float4*>(p + 4);
    }

    f32x4 acc[4];
#pragma unroll
    for (int nt = 0; nt < 4; ++nt) acc[nt] = f32x4{0.f, 0.f, 0.f, 0.f};

#pragma unroll
    for (int ks = 0; ks < 7; ++ks) {
        bf16x8 a;
        a[0] = (__bf16)f0[ks].x; a[1] = (__bf16)f0[ks].y;
        a[2] = (__bf16)f0[ks].z; a[3] = (__bf16)f0[ks].w;
        a[4] = (__bf16)f1[ks].x; a[5] = (__bf16)f1[ks].y;
        a[6] = (__bf16)f1[ks].z; a[7] = (__bf16)f1[ks].w;
#pragma unroll
        for (int nt = 0; nt < 4; ++nt) {
            bf16x8 w = wlds[(ks * 4 + nt) * 64 + lane];
            acc[nt] = __builtin_amdgcn_mfma_f32_16x16x32_bf16(a, w, acc[nt], 0, 0, 0);
        }
    }

    if (!active) return;

    // D layout (m89): col = lane&15 (+16*nt), row = (lane>>4)*4 + j
    const long rb = (long)tile * 16;
#pragma unroll
    for (int nt = 0; nt < 4; ++nt) {
#pragma unroll
        for (int j = 0; j < 4; ++j) {
            float v = acc[nt][j] + bias_v[nt];
            out[(rb + lg * 4 + j) * DOUT_ + nt * 16 + lr] = v > 0.f ? v : 0.f;
        }
    }
}

extern "C" void kernel_launch(void* const* d_in, const int* in_sizes, int n_in,
                              void* d_out, int out_size, void* d_ws, size_t ws_size,
                              hipStream_t stream) {
    const float* edata = (const float*)d_in[0];
    const float* vdata = (const float*)d_in[1];
    const float* cdata = (const float*)d_in[2];
    const int*   snd   = (const int*)d_in[3];
    const int*   rcv   = (const int*)d_in[4];
    const float* W     = (const float*)d_in[5];
    const float* bias  = (const float*)d_in[6];
    float* out = (float*)d_out;

    const int Etot = in_sizes[3];              // B*E = 800000
    const int Bb   = in_sizes[2] / DC_;        // 2
    const int E    = Etot / Bb;                // 400000
    const int NV   = in_sizes[1] / (Bb * DV_); // 50000
    const int n_tiles = (Etot + 15) / 16;      // 50000
    const int tiles_per_batch = E / 16;        // 25000

    __bf16* wf = (__bf16*)d_ws;                // 28 KB fragment buffer

    hipLaunchKernelGGL(prep_w_kernel, dim3(NFRAG), dim3(64), 0, stream, W, wf);

    const int waves_per_block = 16;            // 1024 threads
    const int blocks = (n_tiles + waves_per_block - 1) / waves_per_block;
    hipLaunchKernelGGL(edge_mlp_kernel, dim3(blocks), dim3(1024), 0, stream,
                       edata, vdata, cdata, snd, rcv, wf, bias, out,
                       NV, n_tiles, tiles_per_batch);
}

// Round 5
// 120.896 us; speedup vs baseline: 1.1273x; 1.1083x over previous
//
#include <hip/hip_runtime.h>
#include <hip/hip_bf16.h>

typedef __bf16 bf16x8 __attribute__((ext_vector_type(8)));
typedef float  f32x4  __attribute__((ext_vector_type(4)));
typedef unsigned short ushort;

#define DE_   64
#define DV_   64
#define DC_   32
#define DOUT_ 64
#define DIN_  224
#define NFRAG 28   // 7 k-steps * 4 n-tiles

// Pre-swizzle W ([224][64] f32 row-major) into bf16 MFMA B-fragment order:
// frag f = ks*4+nt ; lane holds B[k][col] with col = nt*16+(lane&15),
// k = ks*32 + (lane>>4)*8 + j, j=0..7 contiguous -> 16B per lane.
__global__ void prep_w_kernel(const float* __restrict__ W, __bf16* __restrict__ wf) {
    int f    = blockIdx.x;          // 0..27
    int lane = threadIdx.x;         // 0..63
    int ks = f >> 2, nt = f & 3;
    int col = nt * 16 + (lane & 15);
    int k0  = ks * 32 + (lane >> 4) * 8;
    bf16x8 v;
#pragma unroll
    for (int j = 0; j < 8; ++j)
        v[j] = (__bf16)W[(k0 + j) * DOUT_ + col];
    reinterpret_cast<bf16x8*>(wf)[f * 64 + lane] = v;
}

// Convert vdata fp32 -> bf16 (halves gather traffic; gathers then feed MFMA
// A-fragments directly with no per-edge cvt).
__global__ void prep_v_kernel(const float* __restrict__ vdata,
                              __bf16* __restrict__ vb16, int n8) {
    int i = blockIdx.x * blockDim.x + threadIdx.x;
    if (i >= n8) return;
    float4 a = reinterpret_cast<const float4*>(vdata)[2 * i];
    float4 b = reinterpret_cast<const float4*>(vdata)[2 * i + 1];
    bf16x8 v;
    v[0] = (__bf16)a.x; v[1] = (__bf16)a.y; v[2] = (__bf16)a.z; v[3] = (__bf16)a.w;
    v[4] = (__bf16)b.x; v[5] = (__bf16)b.y; v[6] = (__bf16)b.z; v[7] = (__bf16)b.w;
    reinterpret_cast<bf16x8*>(vb16)[i] = v;
}

// One wave per 16-edge tile. 1024-thread blocks (16 waves): 28 KB LDS W-copy
// amortized over 16 waves, 2 blocks/CU = 32 waves/CU.
__global__ __launch_bounds__(1024, 2)
void edge_mlp_kernel(const float* __restrict__ edata,
                     const __bf16* __restrict__ vb16,
                     const float* __restrict__ cdata,
                     const int*   __restrict__ snd,
                     const int*   __restrict__ rcv,
                     const __bf16* __restrict__ wf,
                     const float* __restrict__ bias,
                     float* __restrict__ out,
                     int NV, int n_tiles, int tiles_per_batch) {
    __shared__ bf16x8 wlds[NFRAG * 64];   // 28 KB

    const int tid  = threadIdx.x;
    const int lane = tid & 63;
    const int tile = blockIdx.x * (blockDim.x >> 6) + (tid >> 6);
    const bool active = tile < n_tiles;

    const int lr = lane & 15;   // A-row within tile / D-col within n-tile
    const int lg = lane >> 4;   // k-group
    const int kl = lg * 8;

    const int  b   = (tile >= tiles_per_batch) ? 1 : 0;
    const long row = active ? ((long)tile * 16 + lr) : 0;

    // Kick off the dependent chain immediately.
    const int s = snd[row];
    const int r = rcv[row];

    // Independent loads: edata (ks=0,1) and context (ks=6).
    float4 f0[3], f1[3];
#pragma unroll
    for (int ks = 0; ks < 2; ++ks) {
        const float* p = edata + row * DE_ + ks * 32 + kl;
        f0[ks] = *reinterpret_cast<const float4*>(p);
        f1[ks] = *reinterpret_cast<const float4*>(p + 4);
    }
    {
        const float* p = cdata + b * DC_ + kl;
        f0[2] = *reinterpret_cast<const float4*>(p);
        f1[2] = *reinterpret_cast<const float4*>(p + 4);
    }
    float bias_v[4];
#pragma unroll
    for (int nt = 0; nt < 4; ++nt) bias_v[nt] = bias[nt * 16 + lr];

    // Stage W into LDS (hides id-load latency under this + the barrier).
    {
        const bf16x8* wsrc = reinterpret_cast<const bf16x8*>(wf);
        for (int i = tid; i < NFRAG * 64; i += 1024)
            wlds[i] = wsrc[i];
    }
    __syncthreads();

    // Gathered loads, already bf16: one 16B load per lane per k-step.
    const __bf16* vbb = vb16 + (long)b * NV * DV_;
    bf16x8 afrag[7];
#pragma unroll
    for (int ks = 2; ks < 6; ++ks) {
        const __bf16* p = (ks < 4) ? (vbb + (long)s * DV_ + (ks - 2) * 32 + kl)
                                   : (vbb + (long)r * DV_ + (ks - 4) * 32 + kl);
        afrag[ks] = *reinterpret_cast<const bf16x8*>(p);
    }
    // Convert the fp32 streams.
#pragma unroll
    for (int q = 0; q < 3; ++q) {
        int ks = (q < 2) ? q : 6;
        bf16x8 a;
        a[0] = (__bf16)f0[q].x; a[1] = (__bf16)f0[q].y;
        a[2] = (__bf16)f0[q].z; a[3] = (__bf16)f0[q].w;
        a[4] = (__bf16)f1[q].x; a[5] = (__bf16)f1[q].y;
        a[6] = (__bf16)f1[q].z; a[7] = (__bf16)f1[q].w;
        afrag[ks] = a;
    }

    f32x4 acc[4];
#pragma unroll
    for (int nt = 0; nt < 4; ++nt) acc[nt] = f32x4{0.f, 0.f, 0.f, 0.f};

#pragma unroll
    for (int ks = 0; ks < 7; ++ks) {
#pragma unroll
        for (int nt = 0; nt < 4; ++nt) {
            bf16x8 w = wlds[(ks * 4 + nt) * 64 + lane];
            acc[nt] = __builtin_amdgcn_mfma_f32_16x16x32_bf16(afrag[ks], w, acc[nt], 0, 0, 0);
        }
    }

    if (!active) return;

    // D layout (m89): col = lane&15 (+16*nt), row = (lane>>4)*4 + j
    const long rb = (long)tile * 16;
#pragma unroll
    for (int nt = 0; nt < 4; ++nt) {
#pragma unroll
        for (int j = 0; j < 4; ++j) {
            float v = acc[nt][j] + bias_v[nt];
            out[(rb + lg * 4 + j) * DOUT_ + nt * 16 + lr] = v > 0.f ? v : 0.f;
        }
    }
}

extern "C" void kernel_launch(void* const* d_in, const int* in_sizes, int n_in,
                              void* d_out, int out_size, void* d_ws, size_t ws_size,
                              hipStream_t stream) {
    const float* edata = (const float*)d_in[0];
    const float* vdata = (const float*)d_in[1];
    const float* cdata = (const float*)d_in[2];
    const int*   snd   = (const int*)d_in[3];
    const int*   rcv   = (const int*)d_in[4];
    const float* W     = (const float*)d_in[5];
    const float* bias  = (const float*)d_in[6];
    float* out = (float*)d_out;

    const int Etot = in_sizes[3];              // B*E = 800000
    const int Bb   = in_sizes[2] / DC_;        // 2
    const int E    = Etot / Bb;                // 400000
    const int NV   = in_sizes[1] / (Bb * DV_); // 50000
    const int n_tiles = (Etot + 15) / 16;      // 50000
    const int tiles_per_batch = E / 16;        // 25000
    const int nvdata = in_sizes[1];            // B*NV*64 elements

    __bf16* wf   = (__bf16*)d_ws;                          // 28 KB fragments
    __bf16* vb16 = (__bf16*)((char*)d_ws + NFRAG * 64 * 16); // bf16 vdata

    hipLaunchKernelGGL(prep_w_kernel, dim3(NFRAG), dim3(64), 0, stream, W, wf);
    {
        int n8 = nvdata / 8;
        hipLaunchKernelGGL(prep_v_kernel, dim3((n8 + 255) / 256), dim3(256), 0,
                           stream, vdata, vb16, n8);
    }

    const int waves_per_block = 16;            // 1024 threads
    const int blocks = (n_tiles + waves_per_block - 1) / waves_per_block;
    hipLaunchKernelGGL(edge_mlp_kernel, dim3(blocks), dim3(1024), 0, stream,
                       edata, vb16, cdata, snd, rcv, wf, bias, out,
                       NV, n_tiles, tiles_per_batch);
}